// Round 2
// baseline (1294.285 us; speedup 1.0000x reference)
//
#include <hip/hip_runtime.h>
#include <math.h>

#define NEXP 8
#define TTOK 8192
#define DEMB 1024
#define HFF  4096

// ws layout (bytes); full-path need = OFF_HB + 16384*HFF*2 = 151,520,256 (~145 MB)
#define OFF_CNT   0
#define OFF_OFFS  64
#define OFF_PTOK  1024
#define OFF_PW    (OFF_PTOK + NEXP*TTOK*4)
#define OFF_XB    (OFF_PW + NEXP*TTOK*4)
#define OFF_HB    (OFF_XB + TTOK*DEMB*2)

typedef short bf16x8 __attribute__((ext_vector_type(8)));
typedef float f32x4 __attribute__((ext_vector_type(4)));

__device__ __forceinline__ unsigned short f2bf(float f) {
  union { float f; unsigned int u; } v; v.f = f;
  unsigned int r = v.u + 0x7fffu + ((v.u >> 16) & 1u);
  return (unsigned short)(r >> 16);
}

__device__ __forceinline__ void pack4(float4 v, void* dst) {
  uint2 r;
  r.x = (unsigned)f2bf(v.x) | ((unsigned)f2bf(v.y) << 16);
  r.y = (unsigned)f2bf(v.z) | ((unsigned)f2bf(v.w) << 16);
  *(uint2*)dst = r;  // ds_write_b64
}

__device__ __forceinline__ void gll16(const void* g, void* l) {
  __builtin_amdgcn_global_load_lds(
      (const __attribute__((address_space(1))) unsigned int*)g,
      (__attribute__((address_space(3))) unsigned int*)l, 16, 0, 0);
}

// ---------------- X fp32 -> bf16 ----------------
__global__ void k_convert_x(const float* __restrict__ x, ushort4* __restrict__ xb) {
  int i = blockIdx.x * 256 + threadIdx.x;   // grid covers T*D/4 exactly
  float4 v = ((const float4*)x)[i];
  ushort4 o;
  o.x = f2bf(v.x); o.y = f2bf(v.y); o.z = f2bf(v.z); o.w = f2bf(v.w);
  xb[i] = o;
}

// ---------------- gating + top-2 + routing ----------------
__global__ __launch_bounds__(256) void k_gate(
    const float* __restrict__ x, const float* __restrict__ wg,
    int* __restrict__ cnt, int* __restrict__ ptok, float* __restrict__ pw) {
  __shared__ float wgs[NEXP * DEMB];  // 32 KB
  int tid = threadIdx.x;
  for (int i = tid; i < NEXP * DEMB / 4; i += 256)
    ((float4*)wgs)[i] = ((const float4*)wg)[i];
  __syncthreads();
  int lane = tid & 63;
  int t = blockIdx.x * 4 + (tid >> 6);  // one wave per token
  const float* xr = x + (size_t)t * DEMB;
  float acc[NEXP];
#pragma unroll
  for (int e = 0; e < NEXP; ++e) acc[e] = 0.f;
#pragma unroll
  for (int j = 0; j < DEMB / 64; ++j) {
    int d = lane + j * 64;
    float xv = xr[d];
#pragma unroll
    for (int e = 0; e < NEXP; ++e) acc[e] += xv * wgs[e * DEMB + d];
  }
#pragma unroll
  for (int e = 0; e < NEXP; ++e) {
#pragma unroll
    for (int off = 32; off > 0; off >>= 1) acc[e] += __shfl_xor(acc[e], off);
  }
  if (lane == 0) {
    // top-2, lowest-index tie-break (matches lax.top_k)
    float b0 = -1e30f; int i0 = 0;
#pragma unroll
    for (int e = 0; e < NEXP; ++e) if (acc[e] > b0) { b0 = acc[e]; i0 = e; }
    float b1 = -1e30f; int i1 = 0;
#pragma unroll
    for (int e = 0; e < NEXP; ++e) if (e != i0 && acc[e] > b1) { b1 = acc[e]; i1 = e; }
    float ex = expf(b1 - b0);          // b1 <= b0, no overflow
    float s  = 1.f + ex;
    float w0 = 1.f / s;
    float w1v = ex / s;
    int s0 = atomicAdd(&cnt[i0], 1);
    ptok[i0 * TTOK + s0] = t; pw[i0 * TTOK + s0] = w0;
    int s1 = atomicAdd(&cnt[i1], 1);
    ptok[i1 * TTOK + s1] = t; pw[i1 * TTOK + s1] = w1v;
  }
}

// ---------------- exclusive scan over 8 counts ----------------
__global__ void k_scan(const int* __restrict__ cnt, int* __restrict__ offs) {
  if (threadIdx.x == 0) {
    int s = 0;
    for (int e = 0; e < NEXP; ++e) { offs[e] = s; s += cnt[e]; }
  }
}

// Tile decode shared by both GEMMs.
// e_sel < 0 : full path. mt = idp%mTiles, e = (idp/mTiles)%8, nt = idp/(mTiles*8),
//             Hb row = offs[e] + global slot.
// e_sel >= 0: chunked path (expert fixed, rows [mbase, mbase+mTiles*128) of that
//             expert). mt = idp%mTiles, nt = idp/mTiles, Hb row = slot - mbase.

// ---------------- GEMM1: h = silu(X@W1^T) * (X@W3^T) -> Hb (bf16) ----------------
__global__ __launch_bounds__(256, 2) void k_gemm1(
    const unsigned short* __restrict__ Xb, const float* __restrict__ w1,
    const float* __restrict__ w3, const int* __restrict__ cnt,
    const int* __restrict__ offs, const int* __restrict__ ptok,
    unsigned short* __restrict__ Hb, int e_sel, int mbase, int mTiles) {
  int nwg = gridDim.x;
  int orig = blockIdx.x;
  int idp = (orig & 7) * (nwg >> 3) + (orig >> 3);  // bijective (nwg%8==0): XCD-contiguous
  int mt, e, nt;
  if (e_sel >= 0) { e = e_sel; mt = idp % mTiles; nt = idp / mTiles; }
  else { mt = idp % mTiles; e = (idp / mTiles) % NEXP; nt = idp / (mTiles * NEXP); }
  int ce = cnt[e];
  int m0 = mbase + mt * 128;       // global slot base within expert e's list
  if (m0 >= ce) return;
  int n0 = nt * 128;
  int hb = (e_sel >= 0) ? -mbase : offs[e];  // Hb row = hb + global slot

  __shared__ __align__(16) unsigned char sm[49152];
  unsigned char* As = sm;            // 128x64 bf16, XOR-swizzled
  unsigned char* B1 = sm + 16384;
  unsigned char* B3 = sm + 32768;

  int tid = threadIdx.x, lane = tid & 63, wid = tid >> 6;
  int wm = (wid >> 1) * 64, wn = (wid & 1) * 64;
  const float* w1e = w1 + (size_t)e * HFF * DEMB;
  const float* w3e = w3 + (size_t)e * HFF * DEMB;

  // A gather sources: chunk c covers (row=c>>3, colgrp=c&7); source k-group = colgrp ^ (row&7)
  const unsigned short* asrcb[4];
#pragma unroll
  for (int it = 0; it < 4; ++it) {
    int c = it * 256 + tid;
    int row = c >> 3;
    int slot = m0 + row; slot = slot < ce ? slot : ce - 1;
    int tok = ptok[e * TTOK + slot];
    asrcb[it] = Xb + (size_t)tok * DEMB + (size_t)(((c & 7) ^ (row & 7)) * 8);
  }

  const f32x4 zf = {0.f, 0.f, 0.f, 0.f};
  f32x4 au[4][4], av[4][4];
#pragma unroll
  for (int a = 0; a < 4; ++a)
#pragma unroll
    for (int b = 0; b < 4; ++b) { au[a][b] = zf; av[a][b] = zf; }

  for (int kt = 0; kt < DEMB / 64; ++kt) {
    int k0 = kt * 64;
#pragma unroll
    for (int it = 0; it < 4; ++it)
      gll16(asrcb[it] + k0, As + it * 4096 + wid * 1024);
#pragma unroll
    for (int i = 0; i < 8; ++i) {
      int idx = i * 256 + tid;          // 0..2047: n = idx>>4, f4 chunk = idx&15
      int n = idx >> 4, f4 = idx & 15;
      int bb = n * 128 + (((f4 >> 1) ^ (n & 7)) * 16) + (f4 & 1) * 8;
      size_t goff = (size_t)(n0 + n) * DEMB + k0 + f4 * 4;
      pack4(*(const float4*)(w1e + goff), B1 + bb);
      pack4(*(const float4*)(w3e + goff), B3 + bb);
    }
    __syncthreads();
#pragma unroll
    for (int kk = 0; kk < 64; kk += 32) {
      bf16x8 af[4], b1f[4], b3f[4];
      int kg = (kk >> 3) + (lane >> 4);
#pragma unroll
      for (int mr = 0; mr < 4; ++mr) {
        int r = wm + mr * 16 + (lane & 15);
        af[mr] = *(const bf16x8*)(As + r * 128 + ((kg ^ (r & 7)) * 16));
      }
#pragma unroll
      for (int nr = 0; nr < 4; ++nr) {
        int c = wn + nr * 16 + (lane & 15);
        int boff = c * 128 + ((kg ^ (c & 7)) * 16);
        b1f[nr] = *(const bf16x8*)(B1 + boff);
        b3f[nr] = *(const bf16x8*)(B3 + boff);
      }
#pragma unroll
      for (int mr = 0; mr < 4; ++mr)
#pragma unroll
        for (int nr = 0; nr < 4; ++nr) {
          au[mr][nr] = __builtin_amdgcn_mfma_f32_16x16x32_bf16(af[mr], b1f[nr], au[mr][nr], 0, 0, 0);
          av[mr][nr] = __builtin_amdgcn_mfma_f32_16x16x32_bf16(af[mr], b3f[nr], av[mr][nr], 0, 0, 0);
        }
    }
    __syncthreads();
  }
  // epilogue: silu(u)*v -> bf16 Hb ; C layout: col=lane&15, row=(lane>>4)*4+j
#pragma unroll
  for (int mr = 0; mr < 4; ++mr) {
#pragma unroll
    for (int j = 0; j < 4; ++j) {
      int rs = m0 + wm + mr * 16 + (lane >> 4) * 4 + j;
      if (rs < ce) {
        unsigned short* hrow = Hb + (size_t)(hb + rs) * HFF + n0 + wn + (lane & 15);
#pragma unroll
        for (int nr = 0; nr < 4; ++nr) {
          float u = au[mr][nr][j], v = av[mr][nr][j];
          float h = v * (u / (1.f + __expf(-u)));
          hrow[nr * 16] = f2bf(h);
        }
      }
    }
  }
}

// ---------------- GEMM2: out += gate_w * (H @ W2^T) ----------------
__global__ __launch_bounds__(256, 2) void k_gemm2(
    const unsigned short* __restrict__ Hb, const float* __restrict__ w2,
    const int* __restrict__ cnt, const int* __restrict__ offs,
    const int* __restrict__ ptok, const float* __restrict__ pw,
    float* __restrict__ out, int e_sel, int mbase, int mTiles) {
  int nwg = gridDim.x;
  int orig = blockIdx.x;
  int idp = (orig & 7) * (nwg >> 3) + (orig >> 3);
  int mt, e, nt;
  if (e_sel >= 0) { e = e_sel; mt = idp % mTiles; nt = idp / mTiles; }
  else { mt = idp % mTiles; e = (idp / mTiles) % NEXP; nt = idp / (mTiles * NEXP); }
  int ce = cnt[e];
  int m0 = mbase + mt * 128;
  if (m0 >= ce) return;
  int n0 = nt * 128;
  int hb = (e_sel >= 0) ? -mbase : offs[e];

  __shared__ __align__(16) unsigned char sm[32768];
  unsigned char* As = sm;
  unsigned char* B2 = sm + 16384;

  int tid = threadIdx.x, lane = tid & 63, wid = tid >> 6;
  int wm = (wid >> 1) * 64, wn = (wid & 1) * 64;
  const float* w2e = w2 + (size_t)e * DEMB * HFF;

  const unsigned short* asrcb[4];
#pragma unroll
  for (int it = 0; it < 4; ++it) {
    int c = it * 256 + tid;
    int row = c >> 3;
    int slot = m0 + row; slot = slot < ce ? slot : ce - 1;
    asrcb[it] = Hb + (size_t)(hb + slot) * HFF + (size_t)(((c & 7) ^ (row & 7)) * 8);
  }

  const f32x4 zf = {0.f, 0.f, 0.f, 0.f};
  f32x4 acc[4][4];
#pragma unroll
  for (int a = 0; a < 4; ++a)
#pragma unroll
    for (int b = 0; b < 4; ++b) acc[a][b] = zf;

  for (int kt = 0; kt < HFF / 64; ++kt) {
    int k0 = kt * 64;
#pragma unroll
    for (int it = 0; it < 4; ++it)
      gll16(asrcb[it] + k0, As + it * 4096 + wid * 1024);
#pragma unroll
    for (int i = 0; i < 8; ++i) {
      int idx = i * 256 + tid;
      int n = idx >> 4, f4 = idx & 15;
      pack4(*(const float4*)(w2e + (size_t)(n0 + n) * HFF + k0 + f4 * 4),
            B2 + n * 128 + (((f4 >> 1) ^ (n & 7)) * 16) + (f4 & 1) * 8);
    }
    __syncthreads();
#pragma unroll
    for (int kk = 0; kk < 64; kk += 32) {
      bf16x8 af[4], bf_[4];
      int kg = (kk >> 3) + (lane >> 4);
#pragma unroll
      for (int mr = 0; mr < 4; ++mr) {
        int r = wm + mr * 16 + (lane & 15);
        af[mr] = *(const bf16x8*)(As + r * 128 + ((kg ^ (r & 7)) * 16));
      }
#pragma unroll
      for (int nr = 0; nr < 4; ++nr) {
        int c = wn + nr * 16 + (lane & 15);
        bf_[nr] = *(const bf16x8*)(B2 + c * 128 + ((kg ^ (c & 7)) * 16));
      }
#pragma unroll
      for (int mr = 0; mr < 4; ++mr)
#pragma unroll
        for (int nr = 0; nr < 4; ++nr)
          acc[mr][nr] = __builtin_amdgcn_mfma_f32_16x16x32_bf16(af[mr], bf_[nr], acc[mr][nr], 0, 0, 0);
    }
    __syncthreads();
  }
  // epilogue: scale by gate weight, scatter-accumulate (exactly 2 commutative adds/elem)
#pragma unroll
  for (int mr = 0; mr < 4; ++mr) {
#pragma unroll
    for (int j = 0; j < 4; ++j) {
      int rs = m0 + wm + mr * 16 + (lane >> 4) * 4 + j;
      if (rs < ce) {
        int tok = ptok[e * TTOK + rs];
        float gw = pw[e * TTOK + rs];
        float* orow = out + (size_t)tok * DEMB + n0 + wn + (lane & 15);
#pragma unroll
        for (int nr = 0; nr < 4; ++nr)
          atomicAdd(orow + nr * 16, acc[mr][nr][j] * gw);
      }
    }
  }
}

extern "C" void kernel_launch(void* const* d_in, const int* in_sizes, int n_in,
                              void* d_out, int out_size, void* d_ws, size_t ws_size,
                              hipStream_t stream) {
  const float* x  = (const float*)d_in[0];
  const float* wg = (const float*)d_in[1];
  const float* w1 = (const float*)d_in[2];
  const float* w2 = (const float*)d_in[3];
  const float* w3 = (const float*)d_in[4];
  char* ws = (char*)d_ws;
  int*   cnt  = (int*)(ws + OFF_CNT);
  int*   offs = (int*)(ws + OFF_OFFS);
  int*   ptok = (int*)(ws + OFF_PTOK);
  float* pw   = (float*)(ws + OFF_PW);
  unsigned short* Xb = (unsigned short*)(ws + OFF_XB);
  unsigned short* Hb = (unsigned short*)(ws + OFF_HB);
  float* out = (float*)d_out;

  hipMemsetAsync(ws + OFF_CNT, 0, 256, stream);                       // cnt + offs
  hipMemsetAsync(d_out, 0, (size_t)out_size * sizeof(float), stream); // atomic base
  k_convert_x<<<TTOK * DEMB / 4 / 256, 256, 0, stream>>>(x, (ushort4*)Xb);
  k_gate<<<TTOK / 4, 256, 0, stream>>>(x, wg, cnt, ptok, pw);
  k_scan<<<1, 64, 0, stream>>>(cnt, offs);

  // ws-adaptive: full path needs Hb rows for all 2*T routed slots.
  long long hbRows = ((long long)ws_size - OFF_HB) / (HFF * 2);
  if (hbRows >= 2LL * TTOK) {
    // Path A: one compacted Hb, single launches (fast path)
    k_gemm1<<<NEXP * 64 * 32, 256, 0, stream>>>(Xb, w1, w3, cnt, offs, ptok, Hb, -1, 0, 64);
    k_gemm2<<<NEXP * 64 * 8, 256, 0, stream>>>(Hb, w2, cnt, offs, ptok, pw, out, -1, 0, 64);
  } else {
    // Path B: loop (expert, row-chunk), reuse a smaller Hb slab
    int chunkTiles = (int)(hbRows / 128);          // m-tiles that fit in ws
    if (chunkTiles < 1) chunkTiles = 1;            // last resort; assume ws >= ~17.6 MB
    if (chunkTiles > 64) chunkTiles = 64;
    for (int e = 0; e < NEXP; ++e) {
      for (int mb = 0; mb < TTOK; mb += chunkTiles * 128) {
        int mT = chunkTiles;
        if (mb + mT * 128 > TTOK) mT = (TTOK - mb) / 128;
        k_gemm1<<<mT * 32, 256, 0, stream>>>(Xb, w1, w3, cnt, offs, ptok, Hb, e, mb, mT);
        k_gemm2<<<mT * 8, 256, 0, stream>>>(Hb, w2, cnt, offs, ptok, pw, out, e, mb, mT);
      }
    }
  }
}

// Round 3
// 1135.116 us; speedup vs baseline: 1.1402x; 1.1402x over previous
//
#include <hip/hip_runtime.h>
#include <math.h>

#define NEXP 8
#define TTOK 8192
#define DEMB 1024
#define HFF  4096

// ws layout (bytes)
#define OFF_CNT   0
#define OFF_OFFS  64
#define OFF_PTOK  1024
#define OFF_PW    (OFF_PTOK + NEXP*TTOK*4)                 // 263,168
#define OFF_XB    (OFF_PW + NEXP*TTOK*4)                   // 525,312
#define OFF_WB    (OFF_XB + (size_t)TTOK*DEMB*2)           // 17,302,528
// Tier A: Wb(all experts, 201.3MB) then Hb(134.2MB): total ~352.8MB
// Tier C: Wb(one expert, 25.2MB) then Hb per-expert (<=67.1MB): total ~109.6MB

typedef short bf16x8 __attribute__((ext_vector_type(8)));
typedef float f32x4 __attribute__((ext_vector_type(4)));

__device__ __forceinline__ unsigned short f2bf(float f) {
  union { float f; unsigned int u; } v; v.f = f;
  unsigned int r = v.u + 0x7fffu + ((v.u >> 16) & 1u);
  return (unsigned short)(r >> 16);
}

__device__ __forceinline__ void gll16(const void* g, void* l) {
  __builtin_amdgcn_global_load_lds(
      (const __attribute__((address_space(1))) unsigned int*)g,
      (__attribute__((address_space(3))) unsigned int*)l, 16, 0, 0);
}

// ---------------- weights fp32 -> bf16 (8 elems/thread, grid exact) ----------------
__global__ void k_convert_w(const float* __restrict__ w, uint4* __restrict__ wb) {
  size_t i = (size_t)blockIdx.x * 256 + threadIdx.x;
  float4 a = ((const float4*)w)[2 * i];
  float4 b = ((const float4*)w)[2 * i + 1];
  uint4 o;
  o.x = (unsigned)f2bf(a.x) | ((unsigned)f2bf(a.y) << 16);
  o.y = (unsigned)f2bf(a.z) | ((unsigned)f2bf(a.w) << 16);
  o.z = (unsigned)f2bf(b.x) | ((unsigned)f2bf(b.y) << 16);
  o.w = (unsigned)f2bf(b.z) | ((unsigned)f2bf(b.w) << 16);
  wb[i] = o;
}

// ---------------- gating + top-2 + routing + X->bf16 ----------------
__global__ __launch_bounds__(256) void k_gate(
    const float* __restrict__ x, const float* __restrict__ wg,
    int* __restrict__ cnt, int* __restrict__ ptok, float* __restrict__ pw,
    unsigned short* __restrict__ xb) {
  __shared__ float wgs[NEXP * DEMB];  // 32 KB
  int tid = threadIdx.x;
  for (int i = tid; i < NEXP * DEMB / 4; i += 256)
    ((float4*)wgs)[i] = ((const float4*)wg)[i];
  __syncthreads();
  int lane = tid & 63;
  int t = blockIdx.x * 4 + (tid >> 6);  // one wave per token
  const float* xr = x + (size_t)t * DEMB;
  unsigned short* xbr = xb + (size_t)t * DEMB;
  float acc[NEXP];
#pragma unroll
  for (int e = 0; e < NEXP; ++e) acc[e] = 0.f;
#pragma unroll
  for (int j = 0; j < 4; ++j) {
    int d = j * 256 + lane * 4;
    float4 v = *(const float4*)(xr + d);
    ushort4 o;
    o.x = f2bf(v.x); o.y = f2bf(v.y); o.z = f2bf(v.z); o.w = f2bf(v.w);
    *(ushort4*)(xbr + d) = o;
#pragma unroll
    for (int e = 0; e < NEXP; ++e) {
      float4 w = *(const float4*)(wgs + e * DEMB + d);
      acc[e] += v.x * w.x + v.y * w.y + v.z * w.z + v.w * w.w;
    }
  }
#pragma unroll
  for (int e = 0; e < NEXP; ++e) {
#pragma unroll
    for (int off = 32; off > 0; off >>= 1) acc[e] += __shfl_xor(acc[e], off);
  }
  if (lane == 0) {
    // top-2, lowest-index tie-break (matches lax.top_k)
    float b0 = -1e30f; int i0 = 0;
#pragma unroll
    for (int e = 0; e < NEXP; ++e) if (acc[e] > b0) { b0 = acc[e]; i0 = e; }
    float b1 = -1e30f; int i1 = 0;
#pragma unroll
    for (int e = 0; e < NEXP; ++e) if (e != i0 && acc[e] > b1) { b1 = acc[e]; i1 = e; }
    float ex = expf(b1 - b0);          // b1 <= b0, no overflow
    float s  = 1.f + ex;
    float w0 = 1.f / s;
    float w1v = ex / s;
    int s0 = atomicAdd(&cnt[i0], 1);
    ptok[i0 * TTOK + s0] = t; pw[i0 * TTOK + s0] = w0;
    int s1 = atomicAdd(&cnt[i1], 1);
    ptok[i1 * TTOK + s1] = t; pw[i1 * TTOK + s1] = w1v;
  }
}

// ---------------- exclusive scan over 8 counts ----------------
__global__ void k_scan(const int* __restrict__ cnt, int* __restrict__ offs) {
  if (threadIdx.x == 0) {
    int s = 0;
    for (int e = 0; e < NEXP; ++e) { offs[e] = s; s += cnt[e]; }
  }
}

// Tile decode shared by both GEMMs.
// e_sel < 0 : full path. Hb row = offs[e] + slot; weight base offset = e*HFF*DEMB.
// e_sel >= 0: per-expert path (weight slab holds only this expert; Hb row = slot - mbase).

// ---------------- GEMM1: h = silu(X@W1^T) * (X@W3^T) -> Hb (bf16) ----------------
__global__ __launch_bounds__(256, 2) void k_gemm1(
    const unsigned short* __restrict__ Xb, const unsigned short* __restrict__ w1b,
    const unsigned short* __restrict__ w3b, const int* __restrict__ cnt,
    const int* __restrict__ offs, const int* __restrict__ ptok,
    unsigned short* __restrict__ Hb, int e_sel, int mbase, int mTiles) {
  int nwg = gridDim.x;
  int orig = blockIdx.x;
  int idp = (orig & 7) * (nwg >> 3) + (orig >> 3);  // bijective (nwg%8==0), XCD-contiguous
  int mt, e, nt;
  if (e_sel >= 0) { e = e_sel; mt = idp % mTiles; nt = idp / mTiles; }
  else { mt = idp % mTiles; e = (idp / mTiles) % NEXP; nt = idp / (mTiles * NEXP); }
  int ce = cnt[e];
  int m0 = mbase + mt * 128;
  if (m0 >= ce) return;
  int n0 = nt * 128;
  int hb = (e_sel >= 0) ? -mbase : offs[e];
  size_t eo = (size_t)((e_sel >= 0) ? 0 : e) * HFF * DEMB;
  const unsigned short* w1e = w1b + eo;
  const unsigned short* w3e = w3b + eo;

  __shared__ __align__(16) unsigned char sm[49152];
  unsigned char* As = sm;            // 128x64 bf16, involution-swizzled
  unsigned char* B1 = sm + 16384;
  unsigned char* B3 = sm + 32768;

  int tid = threadIdx.x, lane = tid & 63, wid = tid >> 6;
  int wm = (wid >> 1) * 64, wn = (wid & 1) * 64;

  // staging sources: chunk c=(it*256+tid) covers (row=c>>3, colgrp=c&7);
  // source k-group = colgrp ^ (row&7) (involution; read side applies same XOR)
  const unsigned short *as[4], *b1s[4], *b3s[4];
#pragma unroll
  for (int it = 0; it < 4; ++it) {
    int c = it * 256 + tid;
    int row = c >> 3;
    int col = ((c & 7) ^ (row & 7)) * 8;
    int slot = m0 + row; slot = slot < ce ? slot : ce - 1;
    int tok = ptok[e * TTOK + slot];
    as[it]  = Xb + (size_t)tok * DEMB + col;
    b1s[it] = w1e + (size_t)(n0 + row) * DEMB + col;
    b3s[it] = w3e + (size_t)(n0 + row) * DEMB + col;
  }

  const f32x4 zf = {0.f, 0.f, 0.f, 0.f};
  f32x4 au[4][4], av[4][4];
#pragma unroll
  for (int a = 0; a < 4; ++a)
#pragma unroll
    for (int b = 0; b < 4; ++b) { au[a][b] = zf; av[a][b] = zf; }

  for (int kt = 0; kt < DEMB / 64; ++kt) {
    int k0 = kt * 64;
#pragma unroll
    for (int it = 0; it < 4; ++it) gll16(as[it] + k0,  As + it * 4096 + wid * 1024);
#pragma unroll
    for (int it = 0; it < 4; ++it) gll16(b1s[it] + k0, B1 + it * 4096 + wid * 1024);
#pragma unroll
    for (int it = 0; it < 4; ++it) gll16(b3s[it] + k0, B3 + it * 4096 + wid * 1024);
    __syncthreads();
#pragma unroll
    for (int kk = 0; kk < 64; kk += 32) {
      bf16x8 af[4], b1f[4], b3f[4];
      int kg = (kk >> 3) + (lane >> 4);
#pragma unroll
      for (int mr = 0; mr < 4; ++mr) {
        int r = wm + mr * 16 + (lane & 15);
        af[mr] = *(const bf16x8*)(As + r * 128 + ((kg ^ (r & 7)) * 16));
      }
#pragma unroll
      for (int nr = 0; nr < 4; ++nr) {
        int c = wn + nr * 16 + (lane & 15);
        int boff = c * 128 + ((kg ^ (c & 7)) * 16);
        b1f[nr] = *(const bf16x8*)(B1 + boff);
        b3f[nr] = *(const bf16x8*)(B3 + boff);
      }
#pragma unroll
      for (int mr = 0; mr < 4; ++mr)
#pragma unroll
        for (int nr = 0; nr < 4; ++nr) {
          au[mr][nr] = __builtin_amdgcn_mfma_f32_16x16x32_bf16(af[mr], b1f[nr], au[mr][nr], 0, 0, 0);
          av[mr][nr] = __builtin_amdgcn_mfma_f32_16x16x32_bf16(af[mr], b3f[nr], av[mr][nr], 0, 0, 0);
        }
    }
    __syncthreads();
  }
  // epilogue: silu(u)*v -> bf16 Hb ; C layout: col=lane&15, row=(lane>>4)*4+j
#pragma unroll
  for (int mr = 0; mr < 4; ++mr) {
#pragma unroll
    for (int j = 0; j < 4; ++j) {
      int rs = m0 + wm + mr * 16 + (lane >> 4) * 4 + j;
      if (rs < ce) {
        unsigned short* hrow = Hb + (size_t)(hb + rs) * HFF + n0 + wn + (lane & 15);
#pragma unroll
        for (int nr = 0; nr < 4; ++nr) {
          float u = au[mr][nr][j], v = av[mr][nr][j];
          float h = v * (u / (1.f + __expf(-u)));
          hrow[nr * 16] = f2bf(h);
        }
      }
    }
  }
}

// ---------------- GEMM2: out += gate_w * (H @ W2^T) ----------------
__global__ __launch_bounds__(256, 2) void k_gemm2(
    const unsigned short* __restrict__ Hb, const unsigned short* __restrict__ w2b,
    const int* __restrict__ cnt, const int* __restrict__ offs,
    const int* __restrict__ ptok, const float* __restrict__ pw,
    float* __restrict__ out, int e_sel, int mbase, int mTiles) {
  int nwg = gridDim.x;
  int orig = blockIdx.x;
  int idp = (orig & 7) * (nwg >> 3) + (orig >> 3);
  int mt, e, nt;
  if (e_sel >= 0) { e = e_sel; mt = idp % mTiles; nt = idp / mTiles; }
  else { mt = idp % mTiles; e = (idp / mTiles) % NEXP; nt = idp / (mTiles * NEXP); }
  int ce = cnt[e];
  int m0 = mbase + mt * 128;
  if (m0 >= ce) return;
  int n0 = nt * 128;
  int hb = (e_sel >= 0) ? -mbase : offs[e];
  size_t eo = (size_t)((e_sel >= 0) ? 0 : e) * DEMB * HFF;
  const unsigned short* w2e = w2b + eo;

  __shared__ __align__(16) unsigned char sm[32768];
  unsigned char* As = sm;
  unsigned char* B2 = sm + 16384;

  int tid = threadIdx.x, lane = tid & 63, wid = tid >> 6;
  int wm = (wid >> 1) * 64, wn = (wid & 1) * 64;

  const unsigned short *as[4], *b2s[4];
#pragma unroll
  for (int it = 0; it < 4; ++it) {
    int c = it * 256 + tid;
    int row = c >> 3;
    int col = ((c & 7) ^ (row & 7)) * 8;
    int slot = m0 + row; slot = slot < ce ? slot : ce - 1;
    as[it]  = Hb + (size_t)(hb + slot) * HFF + col;
    b2s[it] = w2e + (size_t)(n0 + row) * HFF + col;
  }

  const f32x4 zf = {0.f, 0.f, 0.f, 0.f};
  f32x4 acc[4][4];
#pragma unroll
  for (int a = 0; a < 4; ++a)
#pragma unroll
    for (int b = 0; b < 4; ++b) acc[a][b] = zf;

  for (int kt = 0; kt < HFF / 64; ++kt) {
    int k0 = kt * 64;
#pragma unroll
    for (int it = 0; it < 4; ++it) gll16(as[it] + k0,  As + it * 4096 + wid * 1024);
#pragma unroll
    for (int it = 0; it < 4; ++it) gll16(b2s[it] + k0, B2 + it * 4096 + wid * 1024);
    __syncthreads();
#pragma unroll
    for (int kk = 0; kk < 64; kk += 32) {
      bf16x8 af[4], bf_[4];
      int kg = (kk >> 3) + (lane >> 4);
#pragma unroll
      for (int mr = 0; mr < 4; ++mr) {
        int r = wm + mr * 16 + (lane & 15);
        af[mr] = *(const bf16x8*)(As + r * 128 + ((kg ^ (r & 7)) * 16));
      }
#pragma unroll
      for (int nr = 0; nr < 4; ++nr) {
        int c = wn + nr * 16 + (lane & 15);
        bf_[nr] = *(const bf16x8*)(B2 + c * 128 + ((kg ^ (c & 7)) * 16));
      }
#pragma unroll
      for (int mr = 0; mr < 4; ++mr)
#pragma unroll
        for (int nr = 0; nr < 4; ++nr)
          acc[mr][nr] = __builtin_amdgcn_mfma_f32_16x16x32_bf16(af[mr], bf_[nr], acc[mr][nr], 0, 0, 0);
    }
    __syncthreads();
  }
  // epilogue: scale by gate weight, scatter-accumulate (exactly 2 commutative adds/elem)
#pragma unroll
  for (int mr = 0; mr < 4; ++mr) {
#pragma unroll
    for (int j = 0; j < 4; ++j) {
      int rs = m0 + wm + mr * 16 + (lane >> 4) * 4 + j;
      if (rs < ce) {
        int tok = ptok[e * TTOK + rs];
        float gw = pw[e * TTOK + rs];
        float* orow = out + (size_t)tok * DEMB + n0 + wn + (lane & 15);
#pragma unroll
        for (int nr = 0; nr < 4; ++nr)
          atomicAdd(orow + nr * 16, acc[mr][nr][j] * gw);
      }
    }
  }
}

extern "C" void kernel_launch(void* const* d_in, const int* in_sizes, int n_in,
                              void* d_out, int out_size, void* d_ws, size_t ws_size,
                              hipStream_t stream) {
  const float* x  = (const float*)d_in[0];
  const float* wg = (const float*)d_in[1];
  const float* w1 = (const float*)d_in[2];
  const float* w2 = (const float*)d_in[3];
  const float* w3 = (const float*)d_in[4];
  char* ws = (char*)d_ws;
  int*   cnt  = (int*)(ws + OFF_CNT);
  int*   offs = (int*)(ws + OFF_OFFS);
  int*   ptok = (int*)(ws + OFF_PTOK);
  float* pw   = (float*)(ws + OFF_PW);
  unsigned short* Xb = (unsigned short*)(ws + OFF_XB);
  float* out = (float*)d_out;

  const size_t WPE = (size_t)HFF * DEMB;        // elems per expert per matrix
  hipMemsetAsync(ws + OFF_CNT, 0, 256, stream);                       // cnt + offs
  hipMemsetAsync(d_out, 0, (size_t)out_size * sizeof(float), stream); // atomic base
  k_gate<<<TTOK / 4, 256, 0, stream>>>(x, wg, cnt, ptok, pw, Xb);
  k_scan<<<1, 64, 0, stream>>>(cnt, offs);

  size_t needA = OFF_WB + 3 * NEXP * WPE * 2 + (size_t)2 * TTOK * HFF * 2; // ~352.8MB
  if (ws_size >= needA) {
    // Tier A: preconvert all weights, single compacted Hb, one launch per GEMM
    unsigned short* w1b = (unsigned short*)(ws + OFF_WB);
    unsigned short* w3b = w1b + NEXP * WPE;
    unsigned short* w2b = w3b + NEXP * WPE;
    unsigned short* Hb  = w2b + NEXP * WPE;
    int cgrid = (int)(NEXP * WPE / 8 / 256);    // 16384
    k_convert_w<<<cgrid, 256, 0, stream>>>(w1, (uint4*)w1b);
    k_convert_w<<<cgrid, 256, 0, stream>>>(w3, (uint4*)w3b);
    k_convert_w<<<cgrid, 256, 0, stream>>>(w2, (uint4*)w2b);
    k_gemm1<<<NEXP * 64 * 32, 256, 0, stream>>>(Xb, w1b, w3b, cnt, offs, ptok, Hb, -1, 0, 64);
    k_gemm2<<<NEXP * 64 * 8, 256, 0, stream>>>(Hb, w2b, cnt, offs, ptok, pw, out, -1, 0, 64);
  } else {
    // Tier C: per-expert loop — weight slab (25.2MB) + per-expert Hb (<=67.1MB)
    unsigned short* w1b = (unsigned short*)(ws + OFF_WB);
    unsigned short* w3b = w1b + WPE;
    unsigned short* w2b = w3b + WPE;
    unsigned short* Hb  = w2b + WPE;
    size_t offHbC = OFF_WB + 3 * WPE * 2;
    long long hbRows = ((long long)ws_size - (long long)offHbC) / (HFF * 2);
    int chunkTiles = (int)(hbRows / 128);
    if (chunkTiles < 1) chunkTiles = 1;
    if (chunkTiles > 64) chunkTiles = 64;
    int cgrid = (int)(WPE / 8 / 256);           // 2048
    for (int e = 0; e < NEXP; ++e) {
      k_convert_w<<<cgrid, 256, 0, stream>>>(w1 + e * WPE, (uint4*)w1b);
      k_convert_w<<<cgrid, 256, 0, stream>>>(w3 + e * WPE, (uint4*)w3b);
      k_convert_w<<<cgrid, 256, 0, stream>>>(w2 + e * WPE, (uint4*)w2b);
      for (int mb = 0; mb < TTOK; mb += chunkTiles * 128) {
        int mT = chunkTiles;
        if (mb + mT * 128 > TTOK) mT = (TTOK - mb) / 128;
        if (mT < 1) break;
        k_gemm1<<<mT * 32, 256, 0, stream>>>(Xb, w1b, w3b, cnt, offs, ptok, Hb, e, mb, mT);
        k_gemm2<<<mT * 8, 256, 0, stream>>>(Hb, w2b, cnt, offs, ptok, pw, out, e, mb, mT);
      }
    }
  }
}